// Round 10
// baseline (227.399 us; speedup 1.0000x reference)
//
#include <hip/hip_runtime.h>
#include <hip/hip_bf16.h>

#define T_SEQ 2048
#define D_MODEL 1024
#define N_HEADS 16

typedef _Float16 half8 __attribute__((ext_vector_type(8)));
typedef _Float16 half4 __attribute__((ext_vector_type(4)));
typedef _Float16 half2v __attribute__((ext_vector_type(2)));
typedef float floatx4 __attribute__((ext_vector_type(4)));
typedef unsigned short ushort4v __attribute__((ext_vector_type(4)));
typedef unsigned short ushort8v __attribute__((ext_vector_type(8)));

#define LOG2E 1.44269504088896f

__device__ __forceinline__ unsigned short f32_to_bf16(float f) {
  unsigned u = __builtin_bit_cast(unsigned, f);
  u = u + 0x7FFFu + ((u >> 16) & 1u);
  return (unsigned short)(u >> 16);
}
__device__ __forceinline__ float bf16_to_f32(unsigned short h) {
  unsigned u = ((unsigned)h) << 16;
  return __builtin_bit_cast(float, u);
}
__device__ __forceinline__ half2v pk_f16(float a, float b) {
  return __builtin_bit_cast(half2v, __builtin_amdgcn_cvt_pkrtz(a, b));
}

// async 16B/lane global->LDS. lds base must be wave-uniform; HW adds lane*16.
__device__ __forceinline__ void load16_lds(const _Float16* g, _Float16* lds_base, int lane) {
#if __has_builtin(__builtin_amdgcn_global_load_lds)
  __builtin_amdgcn_global_load_lds(
      (const __attribute__((address_space(1))) void*)g,
      (__attribute__((address_space(3))) void*)lds_base, 16, 0, 0);
#else
  *(half8*)(lds_base + lane * 8) = *(const half8*)g;
#endif
}

// ---------------- dtype detection (bf16 vs fp32 inputs) ----------------
__global__ void k_detect(const unsigned short* __restrict__ x, int* __restrict__ flag) {
  __shared__ int cnt;
  if (threadIdx.x == 0) cnt = 0;
  __syncthreads();
  unsigned short v = x[(size_t)threadIdx.x * 2];
  int e = (v >> 7) & 0xFF;
  int ok = (v == 0) || (e >= 100 && e <= 150);
  atomicAdd(&cnt, ok);
  __syncthreads();
  if (threadIdx.x == 0) *flag = (cnt >= 192) ? 1 : 0;  // 1 = bf16 inputs
}

// ---------------- conversions ----------------
// 8 elements/thread, vectorized both paths
__global__ void k_cvt_h8(const void* __restrict__ in, _Float16* __restrict__ out,
                         int n8, const int* __restrict__ flag) {
  int f = *flag;
  int i = blockIdx.x * 256 + threadIdx.x;
  if (i >= n8) return;
  half8 o;
  if (f) {
    ushort8v u = ((const ushort8v*)in)[i];
#pragma unroll
    for (int e = 0; e < 8; ++e) o[e] = (_Float16)bf16_to_f32(u[e]);
  } else {
    floatx4 a = ((const floatx4*)in)[2 * i];
    floatx4 b = ((const floatx4*)in)[2 * i + 1];
#pragma unroll
    for (int e = 0; e < 4; ++e) { o[e] = (_Float16)a[e]; o[e + 4] = (_Float16)b[e]; }
  }
  ((half8*)out)[i] = o;
}

// biases + mask (mask pre-scaled by 2*log2e for exp2-domain softmax)
__global__ void k_cvt3(const void* __restrict__ ba, const void* __restrict__ bp,
                       const void* __restrict__ mk, float* __restrict__ baF,
                       float* __restrict__ bpF, float* __restrict__ mask2,
                       const int* __restrict__ flag) {
  int f = *flag;
  int i = blockIdx.x * 256 + threadIdx.x;
  auto cv = [&](const void* p, int j) {
    return f ? bf16_to_f32(((const unsigned short*)p)[j]) : ((const float*)p)[j];
  };
  if (i < 3072) baF[i] = cv(ba, i);
  else if (i < 4096) bpF[i - 3072] = cv(bp, i - 3072);
  else mask2[i - 4096] = cv(mk, i - 4096) * (2.0f * LOG2E);
}

// out[n*K + k] = (fp16) in[k*N + n]; two weights in one launch
__global__ __launch_bounds__(256) void k_transpose2(
    const void* __restrict__ inA, _Float16* __restrict__ outA,
    const void* __restrict__ inB, _Float16* __restrict__ outB,
    const int* __restrict__ flag) {
  __shared__ float tile[32][33];
  int f = *flag;
  const void* in;
  _Float16* out;
  int N, bid;
  if (blockIdx.x < 3072) { in = inA; out = outA; N = 3072; bid = blockIdx.x; }
  else { in = inB; out = outB; N = 1024; bid = blockIdx.x - 3072; }
  const int K = 1024;
  int nb = N >> 5;
  int bx = bid % nb, by = bid / nb;
  int n0 = bx << 5, k0 = by << 5;
  int c = threadIdx.x & 31, r = threadIdx.x >> 5;
  const float* fin = (const float*)in;
  const unsigned short* uin = (const unsigned short*)in;
#pragma unroll
  for (int i = 0; i < 4; ++i) {
    int kk = r + i * 8;
    size_t idx = (size_t)(k0 + kk) * N + n0 + c;
    tile[kk][c] = f ? bf16_to_f32(uin[idx]) : fin[idx];
  }
  __syncthreads();
#pragma unroll
  for (int i = 0; i < 4; ++i) {
    int nn = r + i * 8;
    out[(size_t)(n0 + nn) * K + k0 + c] = (_Float16)tile[c][nn];
  }
}

// ---------------- GEMM: D[m][n] = sum_k A[m][k]*BT[n][k] + bias[m] ----------------
// 128x128 tile, BK=64; LDS staging XOR-chunk-swizzled (R8 version, unchanged).
__global__ __launch_bounds__(256) void k_gemm(
    const _Float16* __restrict__ A, const _Float16* __restrict__ BT,
    const float* __restrict__ bias, void* __restrict__ D0,
    void* __restrict__ D1, void* __restrict__ D2,
    int M, int N, int K, int outKind, const int* __restrict__ flag) {
  __shared__ _Float16 As[128 * 64] __attribute__((aligned(16)));
  __shared__ _Float16 Bs[128 * 64] __attribute__((aligned(16)));
  const int tid = threadIdx.x;
  const int wave = tid >> 6, lane = tid & 63;
  const int ln = lane & 15, quad = lane >> 4;
  const int bm = blockIdx.y * 128, bn = blockIdx.x * 128;
  const int wm = (wave & 1) * 64, wn = (wave >> 1) * 64;

  const int sr = tid >> 3, scn = (tid & 7) ^ (sr & 7);
  const _Float16* Ag = A + (size_t)(bm + sr) * K + scn * 8;
  const _Float16* Bg = BT + (size_t)(bn + sr) * K + scn * 8;

  floatx4 acc[4][4] = {};

  for (int kt = 0; kt < K; kt += 64) {
    __syncthreads();
#pragma unroll
    for (int i = 0; i < 4; ++i) {
      load16_lds(Ag + kt + (size_t)i * 32 * K, As + (wave * 64 + i * 256) * 8, lane);
      load16_lds(Bg + kt + (size_t)i * 32 * K, Bs + (wave * 64 + i * 256) * 8, lane);
    }
    __syncthreads();
    half8 af[4][2], bf[4][2];
#pragma unroll
    for (int i = 0; i < 4; ++i) {
      int r = wm + i * 16 + ln;
#pragma unroll
      for (int ks = 0; ks < 2; ++ks)
        af[i][ks] = *(const half8*)(As + r * 64 + ((quad + 4 * ks) ^ (r & 7)) * 8);
    }
#pragma unroll
    for (int j = 0; j < 4; ++j) {
      int r = wn + j * 16 + ln;
#pragma unroll
      for (int ks = 0; ks < 2; ++ks)
        bf[j][ks] = *(const half8*)(Bs + r * 64 + ((quad + 4 * ks) ^ (r & 7)) * 8);
    }
#pragma unroll
    for (int ks = 0; ks < 2; ++ks)
#pragma unroll
      for (int i = 0; i < 4; ++i)
#pragma unroll
        for (int j = 0; j < 4; ++j)
          acc[i][j] = __builtin_amdgcn_mfma_f32_16x16x32_f16(af[i][ks], bf[j][ks], acc[i][j], 0, 0, 0);
  }

  if (outKind == 0) {
    _Float16* Qs = (_Float16*)D0;
    _Float16* Ks = (_Float16*)D1;
    _Float16* Vt = (_Float16*)D2;
    const float qsc = 0.125f * LOG2E;  // 1/sqrt(64) and log2e folded into Q
#pragma unroll
    for (int i = 0; i < 4; ++i) {
      int rbase = bm + wm + i * 16 + quad * 4;
      int sect = rbase >> 10;
      int cfeat = rbase & 1023;
      int h = cfeat >> 6, hd = cfeat & 63;
      float bv[4];
#pragma unroll
      for (int r = 0; r < 4; ++r) bv[r] = bias[rbase + r];
#pragma unroll
      for (int j = 0; j < 4; ++j) {
        int col = bn + wn + j * 16 + ln;
        int b = col >> 11, t = col & 2047;
        size_t bh = (size_t)b * N_HEADS + h;
        float v[4];
#pragma unroll
        for (int r = 0; r < 4; ++r) v[r] = acc[i][j][r] + bv[r];
        if (sect == 0) {
          half4 q;
#pragma unroll
          for (int r = 0; r < 4; ++r) q[r] = (_Float16)(v[r] * qsc);
          *(half4*)(Qs + (bh * T_SEQ + t) * 64 + hd) = q;
        } else if (sect == 1) {
          half4 kk4;
#pragma unroll
          for (int r = 0; r < 4; ++r) kk4[r] = (_Float16)v[r];
          *(half4*)(Ks + (bh * T_SEQ + t) * 64 + hd) = kk4;
        } else {
#pragma unroll
          for (int r = 0; r < 4; ++r)
            Vt[(bh * 64 + hd + r) * T_SEQ + t] = (_Float16)v[r];
        }
      }
    }
  } else {
    int mode = (*flag) ? 2 : 1;  // 2: bf16 out, 1: fp32 out
#pragma unroll
    for (int i = 0; i < 4; ++i) {
      int rbase = bm + wm + i * 16 + quad * 4;
      float bv[4];
#pragma unroll
      for (int r = 0; r < 4; ++r) bv[r] = bias[rbase + r];
#pragma unroll
      for (int j = 0; j < 4; ++j) {
        int col = bn + wn + j * 16 + ln;
        float v[4];
#pragma unroll
        for (int r = 0; r < 4; ++r) v[r] = acc[i][j][r] + bv[r];
        if (mode == 1) {
          floatx4 o = {v[0], v[1], v[2], v[3]};
          *(floatx4*)((float*)D0 + (size_t)col * M + rbase) = o;
        } else {
          ushort4v o;
#pragma unroll
          for (int r = 0; r < 4; ++r) o[r] = f32_to_bf16(v[r]);
          *(ushort4v*)((unsigned short*)D0 + (size_t)col * M + rbase) = o;
        }
      }
    }
  }
}

// ---------------- flash attention v4: 2x2 wave split, single-buffer, padded P ----------------
// block = (b, h, 64 q), 4 waves = (qh)x(kh) 32q x 32k quadrants per 64-key tile.
// Single-buffered K/V (dbuf was neutral - R4/m114: wave-level overlap covers it)
// + P rows padded to 40 halves (80 B = 20 words; 20*ln mod 32 spreads bank
// bases, 16B-aligned) -> LDS 26624 B -> 6 blocks/CU (was 4).
// Fixed-reference softmax per wave key-half; end-of-kernel cross-wave merge.
__global__ __launch_bounds__(256, 4) void k_flash(
    const _Float16* __restrict__ Qs, const _Float16* __restrict__ Ks,
    const _Float16* __restrict__ Vt, const float* __restrict__ mask2,
    _Float16* __restrict__ O) {
  __shared__ __attribute__((aligned(16))) char smem[26624];
  _Float16* Kl = (_Float16*)smem;              // [64*64] swizzled
  _Float16* Vl = (_Float16*)(smem + 8192);     // [64*64] swizzled
  _Float16* PlB = (_Float16*)(smem + 16384);   // [4][32*40] per-wave P, padded
  float* Red = (float*)smem;                   // [2][64][36] overlay (post-loop)

  const int tid = threadIdx.x, wave = tid >> 6, lane = tid & 63;
  const int ln = lane & 15, quad = lane >> 4;
  const int qh = wave & 1, kh = wave >> 1;
  const int id = blockIdx.x;
  const int qc = id & 31, h = (id >> 5) & 15, b = id >> 9;
  const size_t bh = (size_t)b * N_HEADS + h;
  const _Float16* Qb = Qs + bh * T_SEQ * 64;
  const _Float16* Kb = Ks + bh * T_SEQ * 64;
  const _Float16* Vb = Vt + bh * 64 * T_SEQ;
  const int q0w = qc * 64 + qh * 32;  // wave's 32-query base

  // Q B-frags (fixed): qf[jq][kk] = Q[q0w + jq*16 + ln][kk*32 + quad*8 + e]
  half8 qf[2][2];
#pragma unroll
  for (int jq = 0; jq < 2; ++jq)
#pragma unroll
    for (int kk = 0; kk < 2; ++kk)
      qf[jq][kk] = *(const half8*)(Qb + (size_t)(q0w + jq * 16 + ln) * 64 + kk * 32 + quad * 8);

  floatx4 Oacc[4][2] = {};        // [jd d-group][jq]: O^T partial (wave's keys)
  float m0[2] = {0.f, 0.f}, li[2] = {0.f, 0.f};

  // staging (all 4 waves cooperate)
  const int sr = tid >> 3, scn = (tid & 7) ^ (sr & 7);
  const _Float16* kp0 = Kb + (size_t)sr * 64 + scn * 8;
  const _Float16* kp1 = kp0 + 32 * 64;
  const _Float16* vp0 = Vb + (size_t)sr * T_SEQ + scn * 8;
  const _Float16* vp1 = vp0 + 32 * T_SEQ;
  const float* mqw = mask2 + (size_t)b * T_SEQ + kh * 32 + quad * 4;  // key-indexed

  _Float16* Pw = PlB + wave * 1280;  // 32 rows x 40 halves

  for (int t = 0; t < 32; ++t) {
    __syncthreads();  // previous tile's LDS reads done
    {
      _Float16* K0 = Kl + (size_t)wave * 512;
      _Float16* V0 = Vl + (size_t)wave * 512;
      load16_lds(kp0, K0, lane);
      load16_lds(kp1, K0 + 2048, lane);
      load16_lds(vp0, V0, lane);
      load16_lds(vp1, V0 + 2048, lane);
      kp0 += 64 * 64; kp1 += 64 * 64; vp0 += 64; vp1 += 64;
    }
    __syncthreads();  // staged

    // S quadrant: s[jk][jq], keys = kh*32 + jk*16 + (quad*4 + r), q = jq*16+ln
    floatx4 s[2][2];
#pragma unroll
    for (int jk = 0; jk < 2; ++jk) {
      const int krow = kh * 32 + jk * 16 + ln;
      half8 kf0 = *(const half8*)(Kl + krow * 64 + ((quad) ^ (krow & 7)) * 8);
      half8 kf1 = *(const half8*)(Kl + krow * 64 + ((4 + quad) ^ (krow & 7)) * 8);
#pragma unroll
      for (int jq = 0; jq < 2; ++jq) {
        floatx4 z = *(const floatx4*)(mqw + jk * 16);  // mask as MFMA C-init
        z = __builtin_amdgcn_mfma_f32_16x16x32_f16(kf0, qf[jq][0], z, 0, 0, 0);
        z = __builtin_amdgcn_mfma_f32_16x16x32_f16(kf1, qf[jq][1], z, 0, 0, 0);
        s[jk][jq] = z;
      }
    }
    mqw += 64;

    if (t == 0) {
      // fixed per-query reference from tile-0 keys of THIS wave's key-half
#pragma unroll
      for (int jq = 0; jq < 2; ++jq) {
        float tm = -__builtin_inff();
#pragma unroll
        for (int jk = 0; jk < 2; ++jk)
#pragma unroll
          for (int r = 0; r < 4; ++r) tm = fmaxf(tm, s[jk][jq][r]);
        tm = fmaxf(tm, __shfl_xor(tm, 16, 64));
        tm = fmaxf(tm, __shfl_xor(tm, 32, 64));
        m0[jq] = fmaxf(tm, -50.f);
      }
    }

#pragma unroll
    for (int jk = 0; jk < 2; ++jk)
#pragma unroll
      for (int jq = 0; jq < 2; ++jq)
#pragma unroll
        for (int r = 0; r < 4; ++r) {
          float p = __builtin_amdgcn_exp2f(s[jk][jq][r] - m0[jq]);
          s[jk][jq][r] = p;
          li[jq] += p;
        }

    // P[q row][key col]: 32x32 fp16 in 40-half rows, XOR(ln&3) chunk swizzle
#pragma unroll
    for (int jk = 0; jk < 2; ++jk)
#pragma unroll
      for (int jq = 0; jq < 2; ++jq) {
        half2v p01 = pk_f16(s[jk][jq][0], s[jk][jq][1]);
        half2v p23 = pk_f16(s[jk][jq][2], s[jk][jq][3]);
        half4 pk = {p01[0], p01[1], p23[0], p23[1]};
        int row = jq * 16 + ln;
        int cw = (jk * 2 + (quad >> 1)) ^ (ln & 3);
        *(half4*)(Pw + row * 40 + cw * 8 + (quad & 1) * 4) = pk;
      }
    asm volatile("" ::: "memory");  // in-order DS pipe: no HW drain needed
    half8 pf[2];
#pragma unroll
    for (int jq = 0; jq < 2; ++jq) {
      int row = jq * 16 + ln;
      pf[jq] = *(const half8*)(Pw + row * 40 + (quad ^ (ln & 3)) * 8);
    }
#pragma unroll
    for (int jd = 0; jd < 4; ++jd) {
      const int vrow = jd * 16 + ln;
      half8 vf = *(const half8*)(Vl + vrow * 64 + ((kh * 4 + quad) ^ (vrow & 7)) * 8);
#pragma unroll
      for (int jq = 0; jq < 2; ++jq)
        Oacc[jd][jq] = __builtin_amdgcn_mfma_f32_16x16x32_f16(vf, pf[jq], Oacc[jd][jq], 0, 0, 0);
    }
  }

  // finish per-wave l (sum across quads = key rows)
#pragma unroll
  for (int jq = 0; jq < 2; ++jq) {
    li[jq] += __shfl_xor(li[jq], 16, 64);
    li[jq] += __shfl_xor(li[jq], 32, 64);
  }

  // cross-wave merge: kh=1 dumps partials to LDS; kh=0 merges and writes
  __syncthreads();
  float* myRed = Red + ((size_t)qh * 64 + lane) * 36;
  if (kh) {
#pragma unroll
    for (int jd = 0; jd < 4; ++jd)
#pragma unroll
      for (int jq = 0; jq < 2; ++jq)
#pragma unroll
        for (int r = 0; r < 4; ++r) myRed[jd * 8 + jq * 4 + r] = Oacc[jd][jq][r];
#pragma unroll
    for (int jq = 0; jq < 2; ++jq) {
      myRed[32 + jq] = m0[jq];
      myRed[34 + jq] = li[jq];
    }
  }
  __syncthreads();
  if (!kh) {
    float sa[2], sb[2], inv[2];
#pragma unroll
    for (int jq = 0; jq < 2; ++jq) {
      float Mb = myRed[32 + jq], lb = myRed[34 + jq];
      float M = fmaxf(m0[jq], Mb);
      sa[jq] = __builtin_amdgcn_exp2f(m0[jq] - M);
      sb[jq] = __builtin_amdgcn_exp2f(Mb - M);
      inv[jq] = 1.f / (li[jq] * sa[jq] + lb * sb[jq]);
    }
#pragma unroll
    for (int jd = 0; jd < 4; ++jd)
#pragma unroll
      for (int jq = 0; jq < 2; ++jq) {
        half4 ov;
#pragma unroll
        for (int r = 0; r < 4; ++r) {
          float v = Oacc[jd][jq][r] * sa[jq] + myRed[jd * 8 + jq * 4 + r] * sb[jq];
          ov[r] = (_Float16)(v * inv[jq]);
        }
        *(half4*)(O + ((size_t)b * T_SEQ + q0w + jq * 16 + ln) * D_MODEL +
                  h * 64 + jd * 16 + quad * 4) = ov;
      }
  }
}

extern "C" void kernel_launch(void* const* d_in, const int* in_sizes, int n_in,
                              void* d_out, int out_size, void* d_ws, size_t ws_size,
                              hipStream_t stream) {
  const void* x      = d_in[0];
  const void* amask  = d_in[1];
  const void* w_attn = d_in[2];
  const void* b_attn = d_in[3];
  const void* w_proj = d_in[4];
  const void* b_proj = d_in[5];

  char* ws = (char*)d_ws;
  size_t off = 0;
  auto alloc = [&](size_t bytes) {
    void* p = ws + off;
    off += (bytes + 255) & ~(size_t)255;
    return p;
  };
  int* flag        = (int*)alloc(256);
  _Float16* Xh     = (_Float16*)alloc((size_t)4096 * 1024 * 2);
  _Float16* WaT    = (_Float16*)alloc((size_t)3072 * 1024 * 2);
  _Float16* WpT    = (_Float16*)alloc((size_t)1024 * 1024 * 2);
  float* baF       = (float*)alloc(3072 * 4);
  float* bpF       = (float*)alloc(1024 * 4);
  float* mask2     = (float*)alloc(4096 * 4);
  _Float16* Qs     = (_Float16*)alloc((size_t)4096 * 1024 * 2);
  _Float16* Ks     = (_Float16*)alloc((size_t)4096 * 1024 * 2);
  _Float16* Vt     = (_Float16*)alloc((size_t)4096 * 1024 * 2);
  _Float16* AttnH  = (_Float16*)alloc((size_t)4096 * 1024 * 2);

  k_detect<<<1, 256, 0, stream>>>((const unsigned short*)x, flag);
  k_cvt_h8<<<(4096 * 1024 / 8) / 256, 256, 0, stream>>>(x, Xh, 4096 * 1024 / 8, flag);
  k_transpose2<<<3072 + 1024, 256, 0, stream>>>(w_attn, WaT, w_proj, WpT, flag);
  k_cvt3<<<32, 256, 0, stream>>>(b_attn, b_proj, amask, baF, bpF, mask2, flag);

  // GEMM1: qkv^T = WaT(3072xK) . Xh(4096xK)^T, fused scatter to Qs/Ks/Vt
  dim3 g1(4096 / 128, 3072 / 128);
  k_gemm<<<g1, 256, 0, stream>>>(WaT, Xh, baF, Qs, Ks, Vt, 3072, 4096, 1024, 0, flag);

  k_flash<<<1024, 256, 0, stream>>>(Qs, Ks, Vt, mask2, AttnH);

  // GEMM2: out^T = WpT(1024xK) . AttnH(4096xK)^T -> d_out [t][1024]
  dim3 g2(4096 / 128, 1024 / 128);
  k_gemm<<<g2, 256, 0, stream>>>(WpT, AttnH, bpF, d_out, nullptr, nullptr, 1024, 4096, 1024, 1, flag);
}